// Round 3
// baseline (444.156 us; speedup 1.0000x reference)
//
#include <hip/hip_runtime.h>

// PoolHiddenNet round 11: barrier-free streaming GEMM ("pool_stream").
// r10 post-mortem: dispatch time == FETCH/574GB/s -- achieved-BW-bound. The
// barrier-lockstep K-loop caps in-flight bytes (~11KB/CU, Little's law), and
// __syncthreads' vmcnt(0) drain defeats any prefetch distance. This round:
//  - B panel (64 cols x all 640 K, bf16, r8 tile layout+XOR) loaded ONCE into
//    LDS (81920 B = exactly half LDS -> 2 blocks/CU), ONE barrier total.
//  - K-loop per wave is barrier-free: A fp32 fragments global->regs in
//    fragment shape (2x dwordx4/frag), dist-2 reg prefetch that truly spans
//    2 iters (compiler emits counted vmcnt, no barrier drain), pk2 convert,
//    4x ds_read_b128 B frags, 16 MFMA. setprio(1) around MFMA (waves desync
//    -> role diversity, attn-style T5 regime).
//  - sibling swizzle: 8 col-siblings of a row-chunk at bids stride-8 -> same
//    XCD, concurrently resident -> A re-reads served by that XCD's L2
//    (8 groups x 327KB = 2.6MB < 4MB).
//  - epilogue per-wave in regs: shfl_xor(16/32) max-reduce over lquad, then
//    atomicMax to out. 64-row wave span covers <=3 segments (s0,s0+1,s0+2).
//  - emb k-tiles (16..19) computed in-body from L2-hot Ws/bs.

typedef __bf16 bf16x8 __attribute__((ext_vector_type(8)));
typedef float floatx4 __attribute__((ext_vector_type(4)));

constexpr int NR = 102400;
constexpr int NG = 2048;
constexpr int E  = 128;
constexpr int H  = 512;
constexpr int KD = 640;
constexpr int BM = 128, BN = 128, BK = 32;   // fallback tile
constexpr int NKT = KD / BK;   // 20
constexpr int KH  = H / BK;    // 16: first emb k-tile

__device__ inline unsigned short f2bf(float f) {
    unsigned u = __float_as_uint(f);
    u += 0x7FFF + ((u >> 16) & 1u);   // RNE (finite inputs)
    return (unsigned short)(u >> 16);
}

// pack two fp32 -> bf16x2, round-half-up: 2x v_add + 1x v_perm_b32
__device__ inline unsigned pk2(float lo, float hi) {
    return __builtin_amdgcn_perm(__float_as_uint(hi) + 0x8000u,
                                 __float_as_uint(lo) + 0x8000u, 0x07060302u);
}

__device__ inline bf16x8 pk8(float4 a, float4 b) {
    union { uint4 u; bf16x8 v; } c;
    c.u.x = pk2(a.x, a.y); c.u.y = pk2(a.z, a.w);
    c.u.z = pk2(b.x, b.y); c.u.w = pk2(b.z, b.w);
    return c.v;
}

// ---------------- prep: segArr + relA (400 blocks) + WmT transpose (80) ----------------
__global__ __launch_bounds__(256) void prep3(
    const float* __restrict__ pos, const int* __restrict__ sse,
    const float* __restrict__ Wm, unsigned short* __restrict__ WmT,
    int* __restrict__ segArr, float* __restrict__ relA)
{
    const int b = blockIdx.x;
    const int t = threadIdx.x;
    __shared__ float tile[64][65];
    if (b < 400) {
        if (!segArr) return;
        const int i = b * 256 + t;
        int l = 0, r = NG + 1;
        while (l < r) { int m = (l + r) >> 1; if (sse[m] <= i) l = m + 1; else r = m; }
        const int g = l - 1;
        segArr[i] = g;
        const int a = sse[g];
        relA[2 * i + 0] = pos[2 * i + 0] - pos[2 * a + 0];
        relA[2 * i + 1] = pos[2 * i + 1] - pos[2 * a + 1];
    } else {
        const int bb = b - 400;             // [0,80): Wm (640x512) -> WmT (512x640) bf16
        const int kb = (bb % 10) * 64, nb = (bb / 10) * 64;
        const int tx = t & 63, tq = t >> 6;
#pragma unroll
        for (int i = 0; i < 16; ++i) {
            const int k = tq * 16 + i;
            tile[k][tx] = Wm[(size_t)(kb + k) * H + nb + tx];
        }
        __syncthreads();
#pragma unroll
        for (int i = 0; i < 16; ++i) {
            const int n = tq * 16 + i;
            WmT[(size_t)(nb + n) * KD + kb + tx] = f2bf(tile[tx][n]);
        }
    }
}

// ---------------- main: barrier-free streaming GEMM + segment-max ----------------
__global__ __launch_bounds__(256, 2) void pool_stream(
    const float* __restrict__ hist_enc,       // (NR, 512) fp32
    const int*   __restrict__ sse,
    const int*   __restrict__ segArr,         // (NR,)
    const float* __restrict__ relA,           // (NR, 2) fp32
    const float* __restrict__ Ws,             // (2, 128)
    const float* __restrict__ bs,             // (128,)
    const unsigned short* __restrict__ WmT,   // (512, 640) bf16
    const float* __restrict__ bm,             // (512,)
    float*       __restrict__ out)            // (2048, 512) fp32, zeroed
{
    // B panel: 20 k-tiles x 64 cols x 32 k, r8-proven tile layout (XOR swizzle
    // keyed on col). 81920 B = exactly half LDS -> 2 blocks/CU.
    __shared__ __attribute__((aligned(16))) unsigned short Bs[NKT * 64 * 32];

    const int t   = threadIdx.x;
    const int bid = blockIdx.x;
    // sibling swizzle: 8 col-siblings of one row-chunk at bids stride 8 ->
    // same XCD (bid%8 round-robin), concurrently resident -> A via L2.
    const int x     = bid & 7;
    const int q     = bid >> 3;          // [0,400)
    const int col   = q & 7;             // column tile [0,8)
    const int chunk = (q >> 3) * 8 + x;  // row chunk  [0,400)
    const int rowBase = chunk * 256;
    const int cTile   = col * 64;

    const int lane  = t & 63;
    const int wv    = t >> 6;            // 4 waves; wave owns 64 rows x 64 cols
    const int lcol  = lane & 15;
    const int lquad = lane >> 4;

    // ---- B panel fill (once): 5120 8-elem chunks, 20 per thread ----
    {
        const unsigned short* src = WmT + (size_t)cTile * KD;
#pragma unroll
        for (int i = 0; i < 20; ++i) {
            const int idx = i * 256 + t;
            const int r = idx / 80, c8 = idx % 80;     // col r, k-chunk c8
            const uint4 v = *(const uint4*)&src[(size_t)r * KD + c8 * 8];
            const int kt = c8 >> 2;
            const int j  = (c8 & 3) ^ ((r >> 1) & 3);  // XOR slot
            *(uint4*)&Bs[kt * 2048 + r * 32 + j * 8] = v;
        }
    }

    // ---- per-wave prologue (overlaps B fill; drained by the one barrier) ----
    const int wbase = rowBase + wv * 64;
    const float* pA[4];
#pragma unroll
    for (int mt = 0; mt < 4; ++mt)
        pA[mt] = hist_enc + (size_t)(wbase + mt * 16 + lcol) * H + lquad * 8;

    float2 relm[4];
#pragma unroll
    for (int mt = 0; mt < 4; ++mt)
        relm[mt] = *(const float2*)&relA[2 * (wbase + mt * 16 + lcol)];

    float bias[4];
#pragma unroll
    for (int nt = 0; nt < 4; ++nt) bias[nt] = bm[cTile + nt * 16 + lcol];

    const int s0 = segArr[wbase];                 // wave-uniform
    const int bA = sse[s0 + 1];
    const int bB = (s0 + 2 <= NG) ? sse[s0 + 2] : 0x7fffffff;

    // dist-2 A prefetch stages: 2 x 4 frags x 8 fp32 = 64 VGPR
    float4 st[2][4][2];
#pragma unroll
    for (int mt = 0; mt < 4; ++mt) {
        st[0][mt][0] = *(const float4*)(pA[mt] + 0);
        st[0][mt][1] = *(const float4*)(pA[mt] + 4);
        st[1][mt][0] = *(const float4*)(pA[mt] + BK);
        st[1][mt][1] = *(const float4*)(pA[mt] + BK + 4);
    }

    __syncthreads();   // the ONLY barrier: Bs visible to all waves

    floatx4 acc[4][4];
#pragma unroll
    for (int m = 0; m < 4; ++m)
#pragma unroll
        for (int n = 0; n < 4; ++n) acc[m][n] = (floatx4){0.f, 0.f, 0.f, 0.f};

    // ---- barrier-free K loop (fully unrolled; all stage indices static) ----
#pragma unroll
    for (int kt = 0; kt < NKT; ++kt) {
        bf16x8 af[4];
        if (kt < KH) {
            // consume stage kt&1 (loads issued 2 iters ago; counted vmcnt wait)
#pragma unroll
            for (int mt = 0; mt < 4; ++mt)
                af[mt] = pk8(st[kt & 1][mt][0], st[kt & 1][mt][1]);
            // reuse the freed stage for kt+2 (hist range only)
            if (kt + 2 < KH) {
#pragma unroll
                for (int mt = 0; mt < 4; ++mt) {
                    st[kt & 1][mt][0] = *(const float4*)(pA[mt] + (kt + 2) * BK);
                    st[kt & 1][mt][1] = *(const float4*)(pA[mt] + (kt + 2) * BK + 4);
                }
            }
        } else {
            // emb tiles: relu(rel @ Ws + bs); Ws/bs are L2-hot broadcasts
            const int e0 = (kt - KH) * BK + lquad * 8;
            const float4 w0a = *(const float4*)&Ws[e0];
            const float4 w0b = *(const float4*)&Ws[e0 + 4];
            const float4 w1a = *(const float4*)&Ws[E + e0];
            const float4 w1b = *(const float4*)&Ws[E + e0 + 4];
            const float4 ba4 = *(const float4*)&bs[e0];
            const float4 bb4 = *(const float4*)&bs[e0 + 4];
#pragma unroll
            for (int mt = 0; mt < 4; ++mt) {
                const float r0 = relm[mt].x, r1 = relm[mt].y;
                float4 fa, fb;
                fa.x = fmaxf(r0 * w0a.x + r1 * w1a.x + ba4.x, 0.f);
                fa.y = fmaxf(r0 * w0a.y + r1 * w1a.y + ba4.y, 0.f);
                fa.z = fmaxf(r0 * w0a.z + r1 * w1a.z + ba4.z, 0.f);
                fa.w = fmaxf(r0 * w0a.w + r1 * w1a.w + ba4.w, 0.f);
                fb.x = fmaxf(r0 * w0b.x + r1 * w1b.x + bb4.x, 0.f);
                fb.y = fmaxf(r0 * w0b.y + r1 * w1b.y + bb4.y, 0.f);
                fb.z = fmaxf(r0 * w0b.z + r1 * w1b.z + bb4.z, 0.f);
                fb.w = fmaxf(r0 * w0b.w + r1 * w1b.w + bb4.w, 0.f);
                af[mt] = pk8(fa, fb);
            }
        }

        bf16x8 bfr[4];
#pragma unroll
        for (int nt = 0; nt < 4; ++nt) {
            const int c  = nt * 16 + lcol;
            const int pc = lquad ^ ((c >> 1) & 3);
            bfr[nt] = *(const bf16x8*)&Bs[kt * 2048 + c * 32 + pc * 8];
        }

        __builtin_amdgcn_s_setprio(1);
#pragma unroll
        for (int mt = 0; mt < 4; ++mt)
#pragma unroll
            for (int nt = 0; nt < 4; ++nt)
                acc[mt][nt] = __builtin_amdgcn_mfma_f32_16x16x32_bf16(af[mt], bfr[nt], acc[mt][nt], 0, 0, 0);
        __builtin_amdgcn_s_setprio(0);
    }

    // ---- epilogue: per-wave reg reduce + global atomicMax (no LDS/barrier) ----
    // lane's rows: wbase + mt*16 + lquad*4 + rr; 64-row span covers <=3 segs.
    float pm0[4] = {0.f, 0.f, 0.f, 0.f};
    float pm1[4] = {0.f, 0.f, 0.f, 0.f};
    float pm2[4] = {0.f, 0.f, 0.f, 0.f};
#pragma unroll
    for (int nt = 0; nt < 4; ++nt) {
#pragma unroll
        for (int mt = 0; mt < 4; ++mt) {
#pragma unroll
            for (int rr = 0; rr < 4; ++rr) {
                const int rowAbs = wbase + mt * 16 + lquad * 4 + rr;
                const float v = fmaxf(acc[mt][nt][rr] + bias[nt], 0.f);
                const bool geA = rowAbs >= bA;
                const bool geB = rowAbs >= bB;
                pm0[nt] = fmaxf(pm0[nt], (!geA)         ? v : 0.f);
                pm1[nt] = fmaxf(pm1[nt], (geA && !geB)  ? v : 0.f);
                pm2[nt] = fmaxf(pm2[nt], (geB)          ? v : 0.f);
            }
        }
    }
#pragma unroll
    for (int s = 0; s < 3; ++s) {
#pragma unroll
        for (int nt = 0; nt < 4; ++nt) {
            float v = (s == 0) ? pm0[nt] : (s == 1) ? pm1[nt] : pm2[nt];
            v = fmaxf(v, __shfl_xor(v, 16));
            v = fmaxf(v, __shfl_xor(v, 32));
            if (lquad == 0 && v > 0.f) {
                float* dst = &out[(size_t)(s0 + s) * H + cTile + nt * 16 + lcol];
                atomicMax((int*)dst, __float_as_int(v));
            }
        }
    }
}

// ---------------- fallback (round-2 kernel; only if ws too small) ----------------
constexpr int LDAF = 40;
__global__ __launch_bounds__(256) void pool_mfma_fb(
    const float* __restrict__ hist_enc, const float* __restrict__ pos,
    const int* __restrict__ sse, const float* __restrict__ Ws,
    const float* __restrict__ bs, const unsigned short* __restrict__ WmT,
    const float* __restrict__ bm, float* __restrict__ out)
{
    __shared__ __attribute__((aligned(16))) unsigned short As[BM][LDAF];
    __shared__ __attribute__((aligned(16))) unsigned short Bsb[BN][LDAF];
    __shared__ float relRow[BM][2];
    __shared__ int   segRow[BM];
    __shared__ int   bnd[3];
    __shared__ int   Pmax[4][BN + 4];

    const int t = threadIdx.x;
    const int cTile = blockIdx.x * BN;
    const int rowBase = blockIdx.y * BM;

    if (t < BM) {
        const int i = rowBase + t;
        int l = 0, r = NG + 1;
        while (l < r) { int m = (l + r) >> 1; if (sse[m] <= i) l = m + 1; else r = m; }
        const int g = l - 1;
        segRow[t] = g;
        const int a = sse[g];
        relRow[t][0] = pos[2 * i + 0] - pos[2 * a + 0];
        relRow[t][1] = pos[2 * i + 1] - pos[2 * a + 1];
    }
    if (t >= BM && t < BM + 3) bnd[t - BM] = BM;
    for (int idx = t; idx < 4 * (BN + 4); idx += 256) ((int*)Pmax)[idx] = 0;
    __syncthreads();
    if (t < BM - 1) {
        const int s0 = segRow[t], s1 = segRow[t + 1];
        if (s1 != s0) bnd[s1 - segRow[0] - 1] = t + 1;
    }

    const int lane = t & 63, wv = t >> 6;
    const int wr = (wv >> 1) * 64, wc = (wv & 1) * 64;
    const int lcol = lane & 15, lquad = lane >> 4;

    floatx4 acc[4][4];
#pragma unroll
    for (int m = 0; m < 4; ++m)
#pragma unroll
        for (int n = 0; n < 4; ++n) acc[m][n] = (floatx4){0.f, 0.f, 0.f, 0.f};

    for (int kt = 0; kt < KD / BK; ++kt) {
        const int k0 = kt * BK;
        float4 av[4]; uint4 bv[2];
        if (k0 < H) {
#pragma unroll
            for (int i = 0; i < 4; ++i) {
                const int idx = i * 256 + t;
                const int row = idx >> 3, kq = (idx & 7) * 4;
                av[i] = *(const float4*)&hist_enc[(size_t)(rowBase + row) * H + k0 + kq];
            }
        } else {
#pragma unroll
            for (int i = 0; i < 4; ++i) {
                const int idx = i * 256 + t;
                const int row = idx >> 3, kq = (idx & 7) * 4;
                const int e = k0 - H + kq;
                const float4 w0 = *(const float4*)&Ws[e];
                const float4 w1 = *(const float4*)&Ws[E + e];
                const float4 b4 = *(const float4*)&bs[e];
                const float r0 = relRow[row][0], r1 = relRow[row][1];
                av[i].x = fmaxf(r0 * w0.x + r1 * w1.x + b4.x, 0.f);
                av[i].y = fmaxf(r0 * w0.y + r1 * w1.y + b4.y, 0.f);
                av[i].z = fmaxf(r0 * w0.z + r1 * w1.z + b4.z, 0.f);
                av[i].w = fmaxf(r0 * w0.w + r1 * w1.w + b4.w, 0.f);
            }
        }
#pragma unroll
        for (int i = 0; i < 2; ++i) {
            const int idx = i * 256 + t;
            const int n = idx >> 2, q = idx & 3;
            bv[i] = *(const uint4*)&WmT[(size_t)(cTile + n) * KD + k0 + q * 8];
        }
        __syncthreads();
#pragma unroll
        for (int i = 0; i < 4; ++i) {
            const int idx = i * 256 + t;
            const int row = idx >> 3, kq = (idx & 7) * 4;
            ushort4 p;
            p.x = f2bf(av[i].x); p.y = f2bf(av[i].y);
            p.z = f2bf(av[i].z); p.w = f2bf(av[i].w);
            *(ushort4*)&As[row][kq] = p;
        }
#pragma unroll
        for (int i = 0; i < 2; ++i) {
            const int idx = i * 256 + t;
            const int n = idx >> 2, q = idx & 3;
            *(uint4*)&Bsb[n][q * 8] = bv[i];
        }
        __syncthreads();

        bf16x8 af[4], bfr[4];
#pragma unroll
        for (int mt = 0; mt < 4; ++mt)
            af[mt] = *(const bf16x8*)&As[wr + mt * 16 + lcol][lquad * 8];
#pragma unroll
        for (int nt = 0; nt < 4; ++nt)
            bfr[nt] = *(const bf16x8*)&Bsb[wc + nt * 16 + lcol][lquad * 8];
#pragma unroll
        for (int mt = 0; mt < 4; ++mt)
#pragma unroll
            for (int nt = 0; nt < 4; ++nt)
                acc[mt][nt] = __builtin_amdgcn_mfma_f32_16x16x32_bf16(af[mt], bfr[nt], acc[mt][nt], 0, 0, 0);
    }

    const int b0 = bnd[0], b1 = bnd[1], b2 = bnd[2];
    const int segBase = segRow[0];
#pragma unroll
    for (int nt = 0; nt < 4; ++nt) {
        const int col = wc + nt * 16 + lcol;
        const float bias = bm[cTile + col];
        float pm[4] = {0.f, 0.f, 0.f, 0.f};
#pragma unroll
        for (int mt = 0; mt < 4; ++mt) {
#pragma unroll
            for (int r = 0; r < 4; ++r) {
                const int lr = wr + mt * 16 + lquad * 4 + r;
                const int ls = (lr >= b0) + (lr >= b1) + (lr >= b2);
                const float v = fmaxf(acc[mt][nt][r] + bias, 0.f);
                pm[ls] = fmaxf(pm[ls], v);
            }
        }
#pragma unroll
        for (int ls = 0; ls < 4; ++ls)
            if (pm[ls] > 0.f) atomicMax(&Pmax[ls][col], __float_as_int(pm[ls]));
    }
    __syncthreads();
    for (int idx = t; idx < 4 * BN; idx += 256) {
        const int ls = idx >> 7, col = idx & 127;
        if (ls > 0 && bnd[ls - 1] >= BM) continue;
        const int seg = segBase + ls;
        const int v = Pmax[ls][col];
        const int gs = sse[seg], ge = sse[seg + 1];
        float* dst = &out[(size_t)seg * H + cTile + col];
        if (gs >= rowBase && ge <= rowBase + BM) *dst = __int_as_float(v);
        else atomicMax((int*)dst, v);
    }
}

extern "C" void kernel_launch(void* const* d_in, const int* in_sizes, int n_in,
                              void* d_out, int out_size, void* d_ws, size_t ws_size,
                              hipStream_t stream) {
    const float* hist_enc = (const float*)d_in[0];
    const float* pos      = (const float*)d_in[1];
    const int*   sse      = (const int*)  d_in[2];
    const float* Ws       = (const float*)d_in[3];
    const float* bs       = (const float*)d_in[4];
    const float* Wm       = (const float*)d_in[5];
    const float* bm       = (const float*)d_in[6];
    float*       out      = (float*)d_out;

    const size_t needWmT = (size_t)H * KD * 2;     // 655,360 B
    const size_t needSeg = (size_t)NR * 4;         // 409,600 B
    const size_t needRel = (size_t)NR * 2 * 4;     // 819,200 B
    unsigned short* WmT  = (unsigned short*)d_ws;
    int*            segA = (int*)  ((char*)d_ws + needWmT);
    float*          relA = (float*)((char*)d_ws + needWmT + needSeg);

    hipMemsetAsync(out, 0, (size_t)out_size * sizeof(float), stream);

    if (ws_size >= needWmT + needSeg + needRel) {
        prep3<<<480, 256, 0, stream>>>(pos, sse, Wm, WmT, segA, relA);
        pool_stream<<<3200, 256, 0, stream>>>(hist_enc, sse, segA, relA, Ws, bs, WmT, bm, out);
    } else {
        prep3<<<480, 256, 0, stream>>>(pos, sse, Wm, WmT, nullptr, nullptr);
        pool_mfma_fb<<<dim3(H / BN, NR / BM), 256, 0, stream>>>(hist_enc, pos, sse, Ws, bs, WmT, bm, out);
    }
}

// Round 4
// 409.913 us; speedup vs baseline: 1.0835x; 1.0835x over previous
//
#include <hip/hip_runtime.h>

// PoolHiddenNet round 12: "pool_flip" -- A full-K in LDS (converted once),
// B streamed from L2, barrier-free K-loop.
// r11 post-mortem: barrier-free stream got FETCH down (108MB) but was
// latency-starved: 8 waves/CU and ~50 VALU + 8 loads of redundant A-work per
// 16 MFMA (x8 col-siblings). Flip the staging: A (64 rows x 640 K bf16 =
// 80 KB) converted fp32->bf16 ONCE into LDS (emb computed there too), ONE
// barrier, then K-loop is {4 ds_read_b128 + 4 global B loads (L2-hot WmT,
// 640KB, resident every XCD) + 16 MFMA} with dist-2 reg prefetch on B and
// zero in-loop conversion VALU. Block = 64 rows x 256 cols (2 col-halves
// sibling-paired on same XCD so the 2nd fp32 A read is L2/L3-hit).

typedef __bf16 bf16x8 __attribute__((ext_vector_type(8)));
typedef float floatx4 __attribute__((ext_vector_type(4)));

constexpr int NR = 102400;
constexpr int NG = 2048;
constexpr int E  = 128;
constexpr int H  = 512;
constexpr int KD = 640;
constexpr int BM = 128, BN = 128, BK = 32;   // fallback tile
constexpr int NKT = KD / BK;   // 20
constexpr int KH  = H / BK;    // 16: first emb k-tile

__device__ inline unsigned short f2bf(float f) {
    unsigned u = __float_as_uint(f);
    u += 0x7FFF + ((u >> 16) & 1u);   // RNE (finite inputs)
    return (unsigned short)(u >> 16);
}

// pack two fp32 -> bf16x2, round-half-up: 2x v_add + 1x v_perm_b32
__device__ inline unsigned pk2(float lo, float hi) {
    return __builtin_amdgcn_perm(__float_as_uint(hi) + 0x8000u,
                                 __float_as_uint(lo) + 0x8000u, 0x07060302u);
}

// ---------------- prep: segArr + relA (400 blocks) + WmT transpose (80) ----------------
__global__ __launch_bounds__(256) void prep3(
    const float* __restrict__ pos, const int* __restrict__ sse,
    const float* __restrict__ Wm, unsigned short* __restrict__ WmT,
    int* __restrict__ segArr, float* __restrict__ relA)
{
    const int b = blockIdx.x;
    const int t = threadIdx.x;
    __shared__ float tile[64][65];
    if (b < 400) {
        if (!segArr) return;
        const int i = b * 256 + t;
        int l = 0, r = NG + 1;
        while (l < r) { int m = (l + r) >> 1; if (sse[m] <= i) l = m + 1; else r = m; }
        const int g = l - 1;
        segArr[i] = g;
        const int a = sse[g];
        relA[2 * i + 0] = pos[2 * i + 0] - pos[2 * a + 0];
        relA[2 * i + 1] = pos[2 * i + 1] - pos[2 * a + 1];
    } else {
        const int bb = b - 400;             // [0,80): Wm (640x512) -> WmT (512x640) bf16
        const int kb = (bb % 10) * 64, nb = (bb / 10) * 64;
        const int tx = t & 63, tq = t >> 6;
#pragma unroll
        for (int i = 0; i < 16; ++i) {
            const int k = tq * 16 + i;
            tile[k][tx] = Wm[(size_t)(kb + k) * H + nb + tx];
        }
        __syncthreads();
#pragma unroll
        for (int i = 0; i < 16; ++i) {
            const int n = tq * 16 + i;
            WmT[(size_t)(nb + n) * KD + kb + tx] = f2bf(tile[tx][n]);
        }
    }
}

// ---------------- main: A-in-LDS full-K, B-from-L2, barrier-free ----------------
__global__ __launch_bounds__(256, 2) void pool_flip(
    const float* __restrict__ hist_enc,       // (NR, 512) fp32
    const int*   __restrict__ sse,
    const int*   __restrict__ segArr,         // (NR,)
    const float* __restrict__ relA,           // (NR, 2) fp32
    const float* __restrict__ Ws,             // (2, 128)
    const float* __restrict__ bs,             // (128,)
    const unsigned short* __restrict__ WmT,   // (512, 640) bf16
    const float* __restrict__ bm,             // (512,)
    float*       __restrict__ out)            // (2048, 512) fp32, zeroed
{
    // A panel: 20 k-tiles x 64 rows x 32 k bf16, r8-proven tile layout
    // (XOR slot keyed on row). 81920 B -> 2 blocks/CU.
    __shared__ __attribute__((aligned(16))) unsigned short As[NKT * 64 * 32];

    const int t   = threadIdx.x;
    const int bid = blockIdx.x;
    // sibling pairing: the 2 col-halves of one row-chunk differ by 8 in bid
    // (same XCD, adjacent) -> 2nd fp32 A read is L2-hit.
    const int x       = bid & 7;
    const int r_      = bid >> 3;            // [0,400)
    const int colTile = r_ & 1;              // [0,2)
    const int chunk   = (r_ >> 1) * 8 + x;   // [0,1600)
    const int rowBase = chunk * 64;
    const int cTile   = colTile * 256;

    const int lane  = t & 63;
    const int wv    = t >> 6;                // 4 waves; wave owns 64 rows x 64 cols
    const int lcol  = lane & 15;
    const int lquad = lane >> 4;
    const int cb    = cTile + wv * 64;       // this wave's column band

    // ---- B dist-2 reg prefetch pointers (plain global loads, L2-hot) ----
    const unsigned short* pB[4];
#pragma unroll
    for (int nt = 0; nt < 4; ++nt)
        pB[nt] = WmT + (size_t)(cb + nt * 16 + lcol) * KD + lquad * 8;

    uint4 sB[2][4];
#pragma unroll
    for (int nt = 0; nt < 4; ++nt) {
        sB[0][nt] = *(const uint4*)(pB[nt]);
        sB[1][nt] = *(const uint4*)(pB[nt] + BK);
    }

    // ---- conversion phase: 64 rows x 640 K -> As (once) ----
    // thread t: row t>>2, quad-lane phys t&3; 16 hist chunks + 4 emb chunks.
    {
        const int row  = t >> 2;
        const int phys = t & 3;
        const int swz  = (row >> 1) & 3;
        const float* src = hist_enc + (size_t)(rowBase + row) * H + phys * 8;
#pragma unroll
        for (int i = 0; i < 16; ++i) {
            const float4 f0 = *(const float4*)(src + i * 32);
            const float4 f1 = *(const float4*)(src + i * 32 + 4);
            uint4 u;
            u.x = pk2(f0.x, f0.y); u.y = pk2(f0.z, f0.w);
            u.z = pk2(f1.x, f1.y); u.w = pk2(f1.z, f1.w);
            // chunk c8 = phys + 4i -> kt = i? No: kt = c8>>2 = i only when
            // phys<4 and c8=phys+4i -> c8>>2 == i. slot j = (c8&3)^swz = phys^swz.
            *(uint4*)&As[i * 2048 + row * 32 + (phys ^ swz) * 8] = u;
        }
        // emb chunks: ce = phys + 4i (i=0..3), kt = 16+i, slot phys^swz
        const float2 rr = *(const float2*)&relA[2 * (size_t)(rowBase + row)];
#pragma unroll
        for (int i = 0; i < 4; ++i) {
            const int e0 = (phys + 4 * i) * 8;
            const float4 w0a = *(const float4*)&Ws[e0];
            const float4 w0b = *(const float4*)&Ws[e0 + 4];
            const float4 w1a = *(const float4*)&Ws[E + e0];
            const float4 w1b = *(const float4*)&Ws[E + e0 + 4];
            const float4 ba4 = *(const float4*)&bs[e0];
            const float4 bb4 = *(const float4*)&bs[e0 + 4];
            float4 fa, fb;
            fa.x = fmaxf(rr.x * w0a.x + rr.y * w1a.x + ba4.x, 0.f);
            fa.y = fmaxf(rr.x * w0a.y + rr.y * w1a.y + ba4.y, 0.f);
            fa.z = fmaxf(rr.x * w0a.z + rr.y * w1a.z + ba4.z, 0.f);
            fa.w = fmaxf(rr.x * w0a.w + rr.y * w1a.w + ba4.w, 0.f);
            fb.x = fmaxf(rr.x * w0b.x + rr.y * w1b.x + bb4.x, 0.f);
            fb.y = fmaxf(rr.x * w0b.y + rr.y * w1b.y + bb4.y, 0.f);
            fb.z = fmaxf(rr.x * w0b.z + rr.y * w1b.z + bb4.z, 0.f);
            fb.w = fmaxf(rr.x * w0b.w + rr.y * w1b.w + bb4.w, 0.f);
            uint4 u;
            u.x = pk2(fa.x, fa.y); u.y = pk2(fa.z, fa.w);
            u.z = pk2(fb.x, fb.y); u.w = pk2(fb.z, fb.w);
            *(uint4*)&As[(16 + i) * 2048 + row * 32 + (phys ^ swz) * 8] = u;
        }
    }

    // per-lane epilogue constants (loads overlap conversion)
    float bias[4];
#pragma unroll
    for (int nt = 0; nt < 4; ++nt) bias[nt] = bm[cb + nt * 16 + lcol];
    const int s0 = segArr[rowBase];               // block-uniform
    const int bA = sse[s0 + 1];
    const int bB = (s0 + 2 <= NG) ? sse[s0 + 2] : 0x7fffffff;

    __syncthreads();   // the ONLY barrier: As visible to all waves

    floatx4 acc[4][4];
#pragma unroll
    for (int m = 0; m < 4; ++m)
#pragma unroll
        for (int n = 0; n < 4; ++n) acc[m][n] = (floatx4){0.f, 0.f, 0.f, 0.f};

    // ---- barrier-free K loop: 4 ds_read + 16 MFMA + 4 B loads (dist-2) ----
#pragma unroll
    for (int kt = 0; kt < NKT; ++kt) {
        bf16x8 af[4];
#pragma unroll
        for (int mt = 0; mt < 4; ++mt) {
            const int R  = mt * 16 + lcol;
            const int pc = lquad ^ ((R >> 1) & 3);
            af[mt] = *(const bf16x8*)&As[kt * 2048 + R * 32 + pc * 8];
        }
        bf16x8 bfr[4];
#pragma unroll
        for (int nt = 0; nt < 4; ++nt) {
            union { uint4 u; bf16x8 v; } c; c.u = sB[kt & 1][nt];
            bfr[nt] = c.v;
        }

        __builtin_amdgcn_s_setprio(1);
#pragma unroll
        for (int mt = 0; mt < 4; ++mt)
#pragma unroll
            for (int nt = 0; nt < 4; ++nt)
                acc[mt][nt] = __builtin_amdgcn_mfma_f32_16x16x32_bf16(af[mt], bfr[nt], acc[mt][nt], 0, 0, 0);
        __builtin_amdgcn_s_setprio(0);

        // refill the freed stage for kt+2 (issued after MFMAs consume it;
        // a full iteration of cover before the vmcnt wait at kt+2)
        if (kt + 2 < NKT) {
#pragma unroll
            for (int nt = 0; nt < 4; ++nt)
                sB[kt & 1][nt] = *(const uint4*)(pB[nt] + (kt + 2) * BK);
        }
    }

    // ---- epilogue: per-wave reg reduce + global atomicMax (r11-proven) ----
    float pm0[4] = {0.f, 0.f, 0.f, 0.f};
    float pm1[4] = {0.f, 0.f, 0.f, 0.f};
    float pm2[4] = {0.f, 0.f, 0.f, 0.f};
#pragma unroll
    for (int nt = 0; nt < 4; ++nt) {
#pragma unroll
        for (int mt = 0; mt < 4; ++mt) {
#pragma unroll
            for (int rr = 0; rr < 4; ++rr) {
                const int rowAbs = rowBase + mt * 16 + lquad * 4 + rr;
                const float v = fmaxf(acc[mt][nt][rr] + bias[nt], 0.f);
                const bool geA = rowAbs >= bA;
                const bool geB = rowAbs >= bB;
                pm0[nt] = fmaxf(pm0[nt], (!geA)        ? v : 0.f);
                pm1[nt] = fmaxf(pm1[nt], (geA && !geB) ? v : 0.f);
                pm2[nt] = fmaxf(pm2[nt], (geB)         ? v : 0.f);
            }
        }
    }
#pragma unroll
    for (int s = 0; s < 3; ++s) {
#pragma unroll
        for (int nt = 0; nt < 4; ++nt) {
            float v = (s == 0) ? pm0[nt] : (s == 1) ? pm1[nt] : pm2[nt];
            v = fmaxf(v, __shfl_xor(v, 16));
            v = fmaxf(v, __shfl_xor(v, 32));
            if (lquad == 0 && v > 0.f) {
                float* dst = &out[(size_t)(s0 + s) * H + cb + nt * 16 + lcol];
                atomicMax((int*)dst, __float_as_int(v));
            }
        }
    }
}

// ---------------- fallback (round-2 kernel; only if ws too small) ----------------
constexpr int LDAF = 40;
__global__ __launch_bounds__(256) void pool_mfma_fb(
    const float* __restrict__ hist_enc, const float* __restrict__ pos,
    const int* __restrict__ sse, const float* __restrict__ Ws,
    const float* __restrict__ bs, const unsigned short* __restrict__ WmT,
    const float* __restrict__ bm, float* __restrict__ out)
{
    __shared__ __attribute__((aligned(16))) unsigned short Asf[BM][LDAF];
    __shared__ __attribute__((aligned(16))) unsigned short Bsb[BN][LDAF];
    __shared__ float relRow[BM][2];
    __shared__ int   segRow[BM];
    __shared__ int   bnd[3];
    __shared__ int   Pmax[4][BN + 4];

    const int t = threadIdx.x;
    const int cTile = blockIdx.x * BN;
    const int rowBase = blockIdx.y * BM;

    if (t < BM) {
        const int i = rowBase + t;
        int l = 0, r = NG + 1;
        while (l < r) { int m = (l + r) >> 1; if (sse[m] <= i) l = m + 1; else r = m; }
        const int g = l - 1;
        segRow[t] = g;
        const int a = sse[g];
        relRow[t][0] = pos[2 * i + 0] - pos[2 * a + 0];
        relRow[t][1] = pos[2 * i + 1] - pos[2 * a + 1];
    }
    if (t >= BM && t < BM + 3) bnd[t - BM] = BM;
    for (int idx = t; idx < 4 * (BN + 4); idx += 256) ((int*)Pmax)[idx] = 0;
    __syncthreads();
    if (t < BM - 1) {
        const int s0 = segRow[t], s1 = segRow[t + 1];
        if (s1 != s0) bnd[s1 - segRow[0] - 1] = t + 1;
    }

    const int lane = t & 63, wv = t >> 6;
    const int wr = (wv >> 1) * 64, wc = (wv & 1) * 64;
    const int lcol = lane & 15, lquad = lane >> 4;

    floatx4 acc[4][4];
#pragma unroll
    for (int m = 0; m < 4; ++m)
#pragma unroll
        for (int n = 0; n < 4; ++n) acc[m][n] = (floatx4){0.f, 0.f, 0.f, 0.f};

    for (int kt = 0; kt < KD / BK; ++kt) {
        const int k0 = kt * BK;
        float4 av[4]; uint4 bv[2];
        if (k0 < H) {
#pragma unroll
            for (int i = 0; i < 4; ++i) {
                const int idx = i * 256 + t;
                const int row = idx >> 3, kq = (idx & 7) * 4;
                av[i] = *(const float4*)&hist_enc[(size_t)(rowBase + row) * H + k0 + kq];
            }
        } else {
#pragma unroll
            for (int i = 0; i < 4; ++i) {
                const int idx = i * 256 + t;
                const int row = idx >> 3, kq = (idx & 7) * 4;
                const int e = k0 - H + kq;
                const float4 w0 = *(const float4*)&Ws[e];
                const float4 w1 = *(const float4*)&Ws[E + e];
                const float4 b4 = *(const float4*)&bs[e];
                const float r0 = relRow[row][0], r1 = relRow[row][1];
                av[i].x = fmaxf(r0 * w0.x + r1 * w1.x + b4.x, 0.f);
                av[i].y = fmaxf(r0 * w0.y + r1 * w1.y + b4.y, 0.f);
                av[i].z = fmaxf(r0 * w0.z + r1 * w1.z + b4.z, 0.f);
                av[i].w = fmaxf(r0 * w0.w + r1 * w1.w + b4.w, 0.f);
            }
        }
#pragma unroll
        for (int i = 0; i < 2; ++i) {
            const int idx = i * 256 + t;
            const int n = idx >> 2, q = idx & 3;
            bv[i] = *(const uint4*)&WmT[(size_t)(cTile + n) * KD + k0 + q * 8];
        }
        __syncthreads();
#pragma unroll
        for (int i = 0; i < 4; ++i) {
            const int idx = i * 256 + t;
            const int row = idx >> 3, kq = (idx & 7) * 4;
            ushort4 p;
            p.x = f2bf(av[i].x); p.y = f2bf(av[i].y);
            p.z = f2bf(av[i].z); p.w = f2bf(av[i].w);
            *(ushort4*)&Asf[row][kq] = p;
        }
#pragma unroll
        for (int i = 0; i < 2; ++i) {
            const int idx = i * 256 + t;
            const int n = idx >> 2, q = idx & 3;
            *(uint4*)&Bsb[n][q * 8] = bv[i];
        }
        __syncthreads();

        bf16x8 af[4], bfr[4];
#pragma unroll
        for (int mt = 0; mt < 4; ++mt)
            af[mt] = *(const bf16x8*)&Asf[wr + mt * 16 + lcol][lquad * 8];
#pragma unroll
        for (int nt = 0; nt < 4; ++nt)
            bfr[nt] = *(const bf16x8*)&Bsb[wc + nt * 16 + lcol][lquad * 8];
#pragma unroll
        for (int mt = 0; mt < 4; ++mt)
#pragma unroll
            for (int nt = 0; nt < 4; ++nt)
                acc[mt][nt] = __builtin_amdgcn_mfma_f32_16x16x32_bf16(af[mt], bfr[nt], acc[mt][nt], 0, 0, 0);
    }

    const int b0 = bnd[0], b1 = bnd[1], b2 = bnd[2];
    const int segBase = segRow[0];
#pragma unroll
    for (int nt = 0; nt < 4; ++nt) {
        const int col = wc + nt * 16 + lcol;
        const float bias = bm[cTile + col];
        float pm[4] = {0.f, 0.f, 0.f, 0.f};
#pragma unroll
        for (int mt = 0; mt < 4; ++mt) {
#pragma unroll
            for (int r = 0; r < 4; ++r) {
                const int lr = wr + mt * 16 + lquad * 4 + r;
                const int ls = (lr >= b0) + (lr >= b1) + (lr >= b2);
                const float v = fmaxf(acc[mt][nt][r] + bias, 0.f);
                pm[ls] = fmaxf(pm[ls], v);
            }
        }
#pragma unroll
        for (int ls = 0; ls < 4; ++ls)
            if (pm[ls] > 0.f) atomicMax(&Pmax[ls][col], __float_as_int(pm[ls]));
    }
    __syncthreads();
    for (int idx = t; idx < 4 * BN; idx += 256) {
        const int ls = idx >> 7, col = idx & 127;
        if (ls > 0 && bnd[ls - 1] >= BM) continue;
        const int seg = segBase + ls;
        const int v = Pmax[ls][col];
        const int gs = sse[seg], ge = sse[seg + 1];
        float* dst = &out[(size_t)seg * H + cTile + col];
        if (gs >= rowBase && ge <= rowBase + BM) *dst = __int_as_float(v);
        else atomicMax((int*)dst, v);
    }
}

extern "C" void kernel_launch(void* const* d_in, const int* in_sizes, int n_in,
                              void* d_out, int out_size, void* d_ws, size_t ws_size,
                              hipStream_t stream) {
    const float* hist_enc = (const float*)d_in[0];
    const float* pos      = (const float*)d_in[1];
    const int*   sse      = (const int*)  d_in[2];
    const float* Ws       = (const float*)d_in[3];
    const float* bs       = (const float*)d_in[4];
    const float* Wm       = (const float*)d_in[5];
    const float* bm       = (const float*)d_in[6];
    float*       out      = (float*)d_out;

    const size_t needWmT = (size_t)H * KD * 2;     // 655,360 B
    const size_t needSeg = (size_t)NR * 4;         // 409,600 B
    const size_t needRel = (size_t)NR * 2 * 4;     // 819,200 B
    unsigned short* WmT  = (unsigned short*)d_ws;
    int*            segA = (int*)  ((char*)d_ws + needWmT);
    float*          relA = (float*)((char*)d_ws + needWmT + needSeg);

    hipMemsetAsync(out, 0, (size_t)out_size * sizeof(float), stream);

    if (ws_size >= needWmT + needSeg + needRel) {
        prep3<<<480, 256, 0, stream>>>(pos, sse, Wm, WmT, segA, relA);
        pool_flip<<<3200, 256, 0, stream>>>(hist_enc, sse, segA, relA, Ws, bs, WmT, bm, out);
    } else {
        prep3<<<480, 256, 0, stream>>>(pos, sse, Wm, WmT, nullptr, nullptr);
        pool_mfma_fb<<<dim3(H / BN, NR / BM), 256, 0, stream>>>(hist_enc, pos, sse, Ws, bs, WmT, bm, out);
    }
}